// Round 2
// baseline (130.944 us; speedup 1.0000x reference)
//
#include <hip/hip_runtime.h>
#include <math.h>

#define NB 32
#define HDIM 512
#define WDIM 512
#define PSTR 32   // floats per batch param block

// 3x3 f32 matmul, fma-ascending-k accumulation (matches BLAS sgemm microkernel)
__device__ inline void mm3(float* C, const float* A, const float* B) {
#pragma unroll
  for (int i = 0; i < 3; ++i) {
#pragma unroll
    for (int j = 0; j < 3; ++j) {
      float acc = __fmaf_rn(A[i*3+0], B[0*3+j], 0.0f);
      acc = __fmaf_rn(A[i*3+1], B[1*3+j], acc);
      acc = __fmaf_rn(A[i*3+2], B[2*3+j], acc);
      C[i*3+j] = acc;
    }
  }
}

// One thread per batch. All arithmetic replicates the reference's f32 chain
// bit-faithfully: trig = f64 computed, rounded once to f32 (correctly-rounded
// f32, matches glibc cosf/sinf); every other op is an explicit IEEE f32
// mul/add/sub in the reference's operation order (no FMA contraction).
__global__ void setup_params(const float* __restrict__ geom,
                             const float* __restrict__ color,
                             const float* __restrict__ cut,
                             float* __restrict__ P) {
  int b = blockIdx.x * blockDim.x + threadIdx.x;
  if (b >= NB) return;

  const float DEGf = (float)(3.14159265358979323846 / 180.0); // np.float32(pi/180)
  const float a15  = 15.0f * DEGf;   // compile-time f32, matches 15*DEG in np
  const float a10  = 10.0f * DEGf;

  // ---- geometry params ----
  const float* g = geom + b * 8;
  float tilt = __fmul_rn(__fsub_rn(__fmul_rn(g[1], 2.0f), 1.0f), a15);
  float pan  = __fmul_rn(__fsub_rn(__fmul_rn(g[2], 2.0f), 1.0f), a15);
  float rotf = __fmul_rn(__fsub_rn(__fmul_rn(g[3], 2.0f), 1.0f), a15);
  float sc   = __fadd_rn(1.0f,
                 __fmul_rn(__fsub_rn(__fmul_rn(g[4], 2.0f), 1.0f), 0.1f));
  float tx   = __fmul_rn(__fsub_rn(__fmul_rn(g[5], 2.0f), 1.0f), 0.2f);
  float ty   = __fmul_rn(__fsub_rn(__fmul_rn(g[6], 2.0f), 1.0f), 0.2f);
  float fx   = (g[0] > 0.5f) ? -1.0f : 1.0f;

  float ct = (float)cos((double)tilt), st = (float)sin((double)tilt);
  float cp = (float)cos((double)pan),  sp = (float)sin((double)pan);
  float cr = (float)cos((double)rotf), sr = (float)sin((double)rotf);

  float sccr = __fmul_rn(sc, cr);
  float scsr = __fmul_rn(sc, sr);

  float F[9]  = {fx, 0.f, 0.f,  0.f, 1.f, 0.f,  0.f, 0.f, 1.f};
  float Rx[9] = {1.f, 0.f, 0.f,  0.f, ct, -st,  0.f, st, ct};
  float Ry[9] = {cp, 0.f, sp,  0.f, 1.f, 0.f,  -sp, 0.f, cp};
  float RS[9] = {sccr, -scsr, 0.f,  scsr, sccr, 0.f,  0.f, 0.f, 1.f};
  float T[9]  = {1.f, 0.f, tx,  0.f, 1.f, ty,  0.f, 0.f, 1.f};

  float t1[9], t2[9], M[9];
  mm3(t1, T, RS);    // T @ RS
  mm3(t2, t1, Rx);   // @ Rx
  mm3(t1, t2, Ry);   // @ Ry
  mm3(M, t1, F);     // @ F

  // ---- color params ----
  const float* c = color + b * 4;
  float theta  = __fmul_rn(__fsub_rn(__fmul_rn(c[0], 2.0f), 1.0f), a10);
  float sat    = __fadd_rn(1.0f,
                   __fmul_rn(__fsub_rn(__fmul_rn(c[1], 2.0f), 1.0f), 0.4f));
  float bright = __fadd_rn(1.0f,
                   __fmul_rn(__fsub_rn(__fmul_rn(c[2], 2.0f), 1.0f), 0.1f));
  float gammaf = __fadd_rn(1.0f,
                   __fmul_rn(__fsub_rn(__fmul_rn(c[3], 2.0f), 1.0f), 0.2f));

  float cth = (float)cos((double)theta), sth = (float)sin((double)theta);
  float omc = __fsub_rn(1.0f, cth);
  float oms = __fsub_rn(1.0f, sat);
  const float aK = (float)(1.0 / sqrt(3.0));       // np.float32(1/sqrt(3))
  const float Af = (float)(1.0 / 3.0);             // np f32(1/3)
  const float K[9]   = {0.f, -aK, aK,  aK, 0.f, -aK,  -aK, aK, 0.f};
  const float lum[3] = {(float)0.299, (float)0.587, (float)0.114};

  float Rh[9], Sm[9], SR[9];
#pragma unroll
  for (int i = 0; i < 3; ++i) {
#pragma unroll
    for (int j = 0; j < 3; ++j) {
      float I = (i == j) ? 1.0f : 0.0f;
      // ((c*I + s*K) + (1-c)*A), each op IEEE f32
      Rh[i*3+j] = __fadd_rn(
          __fadd_rn(__fmul_rn(cth, I), __fmul_rn(sth, K[i*3+j])),
          __fmul_rn(omc, Af));
      Sm[i*3+j] = __fadd_rn(__fmul_rn(sat, I), __fmul_rn(oms, lum[j]));
    }
  }
  mm3(SR, Sm, Rh);

  // ---- store ----
  float* pp = P + b * PSTR;
#pragma unroll
  for (int i = 0; i < 9; ++i) pp[i] = M[i];
#pragma unroll
  for (int i = 0; i < 9; ++i) pp[9 + i] = __fmul_rn(bright, SR[i]);
  pp[18] = gammaf;

  const float* cu = cut + b * 5;
  pp[19] = (cu[0] < 0.5f) ? 1.0f : 0.0f;
  pp[20] = cu[1];
  pp[21] = cu[2];
  // (0.3 + 0.2*u) * 0.5 — exact f32 chain; *0.5 is exact
  pp[22] = __fmul_rn(__fadd_rn(0.3f, __fmul_rn(0.2f, cu[3])), 0.5f);
  pp[23] = __fmul_rn(__fadd_rn(0.3f, __fmul_rn(0.2f, cu[4])), 0.5f);
}

__global__ __launch_bounds__(256) void augment_kernel(
    const float* __restrict__ img, const float* __restrict__ P,
    float* __restrict__ out) {
  const int tid = threadIdx.x;
  const int bkid = blockIdx.x;
  const int bb = bkid >> 10;                 // batch index, block-uniform
  const int p = bkid * 256 + tid;            // global pixel index
  const int rem = p & (HDIM * WDIM - 1);
  const int yy = rem >> 9;
  const int xx = rem & (WDIM - 1);

  const float* pp = P + bb * PSTR;
  const float m00 = pp[0], m01 = pp[1], m02 = pp[2];
  const float m10 = pp[3], m11 = pp[4], m12 = pp[5];
  const float m20 = pp[6], m21 = pp[7], m22 = pp[8];

  // np.linspace(-1,1,512): f64 i*delta + start, cast f32
  const float xs  = (float)((double)xx * (2.0 / 511.0) + (-1.0));
  const float ysv = (float)((double)yy * (2.0 / 511.0) + (-1.0));

  // einsum: ((M0*x + M1*y) + M2), explicit IEEE mul/add, no FMA (matches np)
  const float s0 = __fadd_rn(
      __fadd_rn(__fmul_rn(m00, xs), __fmul_rn(m01, ysv)), m02);
  const float s1 = __fadd_rn(
      __fadd_rn(__fmul_rn(m10, xs), __fmul_rn(m11, ysv)), m12);
  const float s2 = __fadd_rn(
      __fadd_rn(__fmul_rn(m20, xs), __fmul_rn(m21, ysv)), m22);
  const float u = __fdiv_rn(s0, s2);
  const float v = __fdiv_rn(s1, s2);
  const float px = __fmul_rn(__fmul_rn(__fadd_rn(u, 1.0f), 0.5f), 511.0f);
  const float py = __fmul_rn(__fmul_rn(__fadd_rn(v, 1.0f), 0.5f), 511.0f);

  const float vmask =
      (px >= 0.0f && px <= 511.0f && py >= 0.0f && py <= 511.0f) ? 1.0f : 0.0f;

  const float pxc = fminf(fmaxf(px, 0.0f), 511.0f);
  const float pyc = fminf(fmaxf(py, 0.0f), 511.0f);
  const float x0f = floorf(pxc), y0f = floorf(pyc);
  const float wx = pxc - x0f, wy = pyc - y0f;
  const int x0 = (int)x0f, y0 = (int)y0f;
  const int x1 = min(x0 + 1, WDIM - 1);
  const int y1 = min(y0 + 1, HDIM - 1);

  const float* base = img + (size_t)bb * (HDIM * WDIM * 3);
  const float* p00 = base + (y0 * WDIM + x0) * 3;
  const float* p01 = base + (y0 * WDIM + x1) * 3;
  const float* p10 = base + (y1 * WDIM + x0) * 3;
  const float* p11 = base + (y1 * WDIM + x1) * 3;

  float w00 = (1.0f - wx) * (1.0f - wy);
  float w01 = wx * (1.0f - wy);
  float w10 = (1.0f - wx) * wy;
  float w11 = wx * wy;
  w00 *= vmask; w01 *= vmask; w10 *= vmask; w11 *= vmask;

  const float gamma = pp[18];
  float r0, r1, r2;
  {
    float s;
    s = p00[0] * w00 + p01[0] * w01 + p10[0] * w10 + p11[0] * w11;
    s = fminf(fmaxf(s, 0.0f), 1.0f);
    r0 = __powf(s, gamma);
    s = p00[1] * w00 + p01[1] * w01 + p10[1] * w10 + p11[1] * w11;
    s = fminf(fmaxf(s, 0.0f), 1.0f);
    r1 = __powf(s, gamma);
    s = p00[2] * w00 + p01[2] * w01 + p10[2] * w10 + p11[2] * w11;
    s = fminf(fmaxf(s, 0.0f), 1.0f);
    r2 = __powf(s, gamma);
  }

  // color matrix: out[d] = sum_c r[c] * Mc[d][c], then clip
  float q0 = fminf(fmaxf(pp[ 9] * r0 + pp[10] * r1 + pp[11] * r2, 0.0f), 1.0f);
  float q1 = fminf(fmaxf(pp[12] * r0 + pp[13] * r1 + pp[14] * r2, 0.0f), 1.0f);
  float q2 = fminf(fmaxf(pp[15] * r0 + pp[16] * r1 + pp[17] * r2, 0.0f), 1.0f);

  // cutout: linspace(0,1,512) as f64 i*delta, cast f32; compares bit-exact
  const float gx = (float)((double)xx * (1.0 / 511.0));
  const float gy = (float)((double)yy * (1.0 / 511.0));
  const bool cutm = (pp[19] != 0.0f) &&
                    (fabsf(__fsub_rn(gx, pp[20])) < pp[22]) &&
                    (fabsf(__fsub_rn(gy, pp[21])) < pp[23]);
  if (cutm) { q0 = 0.0f; q1 = 0.0f; q2 = 0.0f; }

  const size_t o = (size_t)p * 3;
  out[o + 0] = q0;
  out[o + 1] = q1;
  out[o + 2] = q2;
}

extern "C" void kernel_launch(void* const* d_in, const int* in_sizes, int n_in,
                              void* d_out, int out_size, void* d_ws, size_t ws_size,
                              hipStream_t stream) {
  const float* images = (const float*)d_in[0];
  const float* geom   = (const float*)d_in[1];
  const float* color  = (const float*)d_in[2];
  const float* cutu   = (const float*)d_in[3];
  float* P = (float*)d_ws;   // 32 * 32 * 4 B = 4 KB of scratch

  setup_params<<<1, 64, 0, stream>>>(geom, color, cutu, P);

  const int npix = NB * HDIM * WDIM;
  augment_kernel<<<npix / 256, 256, 0, stream>>>(images, P, (float*)d_out);
}

// Round 3
// 76.524 us; speedup vs baseline: 1.7111x; 1.7111x over previous
//
#include <hip/hip_runtime.h>
#include <math.h>

#define NB 32
#define HDIM 512
#define WDIM 512
#define HW (HDIM * WDIM)
#define PSTR 32   // floats per batch param block
// d_ws layout (floats): [0, NB*PSTR) params | [1024, 1536) lin11 | [1536, 2048) lin01
#define LIN11_OFF 1024
#define LIN01_OFF 1536

// 3x3 f32 matmul, fma-ascending-k accumulation (matches BLAS sgemm microkernel)
__device__ inline void mm3(float* C, const float* A, const float* B) {
#pragma unroll
  for (int i = 0; i < 3; ++i) {
#pragma unroll
    for (int j = 0; j < 3; ++j) {
      float acc = __fmaf_rn(A[i*3+0], B[0*3+j], 0.0f);
      acc = __fmaf_rn(A[i*3+1], B[1*3+j], acc);
      acc = __fmaf_rn(A[i*3+2], B[2*3+j], acc);
      C[i*3+j] = acc;
    }
  }
}

// 512 threads: fill linspace tables; threads 0..31 also build per-batch params.
// Param arithmetic replicates the reference's f32 chain bit-faithfully.
__global__ void setup_params(const float* __restrict__ geom,
                             const float* __restrict__ color,
                             const float* __restrict__ cut,
                             float* __restrict__ W) {
  const int t = threadIdx.x;
  // np.linspace: f64 i*delta + start, cast once to f32
  W[LIN11_OFF + t] = (float)((double)t * (2.0 / 511.0) + (-1.0));
  W[LIN01_OFF + t] = (float)((double)t * (1.0 / 511.0));
  if (t >= NB) return;
  const int b = t;

  const float DEGf = (float)(3.14159265358979323846 / 180.0);
  const float a15  = 15.0f * DEGf;
  const float a10  = 10.0f * DEGf;

  const float* g = geom + b * 8;
  float tilt = __fmul_rn(__fsub_rn(__fmul_rn(g[1], 2.0f), 1.0f), a15);
  float pan  = __fmul_rn(__fsub_rn(__fmul_rn(g[2], 2.0f), 1.0f), a15);
  float rotf = __fmul_rn(__fsub_rn(__fmul_rn(g[3], 2.0f), 1.0f), a15);
  float sc   = __fadd_rn(1.0f,
                 __fmul_rn(__fsub_rn(__fmul_rn(g[4], 2.0f), 1.0f), 0.1f));
  float tx   = __fmul_rn(__fsub_rn(__fmul_rn(g[5], 2.0f), 1.0f), 0.2f);
  float ty   = __fmul_rn(__fsub_rn(__fmul_rn(g[6], 2.0f), 1.0f), 0.2f);
  float fx   = (g[0] > 0.5f) ? -1.0f : 1.0f;

  float ct = (float)cos((double)tilt), st = (float)sin((double)tilt);
  float cp = (float)cos((double)pan),  sp = (float)sin((double)pan);
  float cr = (float)cos((double)rotf), sr = (float)sin((double)rotf);

  float sccr = __fmul_rn(sc, cr);
  float scsr = __fmul_rn(sc, sr);

  float F[9]  = {fx, 0.f, 0.f,  0.f, 1.f, 0.f,  0.f, 0.f, 1.f};
  float Rx[9] = {1.f, 0.f, 0.f,  0.f, ct, -st,  0.f, st, ct};
  float Ry[9] = {cp, 0.f, sp,  0.f, 1.f, 0.f,  -sp, 0.f, cp};
  float RS[9] = {sccr, -scsr, 0.f,  scsr, sccr, 0.f,  0.f, 0.f, 1.f};
  float T[9]  = {1.f, 0.f, tx,  0.f, 1.f, ty,  0.f, 0.f, 1.f};

  float t1[9], t2[9], M[9];
  mm3(t1, T, RS);
  mm3(t2, t1, Rx);
  mm3(t1, t2, Ry);
  mm3(M, t1, F);

  const float* c = color + b * 4;
  float theta  = __fmul_rn(__fsub_rn(__fmul_rn(c[0], 2.0f), 1.0f), a10);
  float sat    = __fadd_rn(1.0f,
                   __fmul_rn(__fsub_rn(__fmul_rn(c[1], 2.0f), 1.0f), 0.4f));
  float bright = __fadd_rn(1.0f,
                   __fmul_rn(__fsub_rn(__fmul_rn(c[2], 2.0f), 1.0f), 0.1f));
  float gammaf = __fadd_rn(1.0f,
                   __fmul_rn(__fsub_rn(__fmul_rn(c[3], 2.0f), 1.0f), 0.2f));

  float cth = (float)cos((double)theta), sth = (float)sin((double)theta);
  float omc = __fsub_rn(1.0f, cth);
  float oms = __fsub_rn(1.0f, sat);
  const float aK = (float)(1.0 / sqrt(3.0));
  const float Af = (float)(1.0 / 3.0);
  const float K[9]   = {0.f, -aK, aK,  aK, 0.f, -aK,  -aK, aK, 0.f};
  const float lum[3] = {(float)0.299, (float)0.587, (float)0.114};

  float Rh[9], Sm[9], SR[9];
#pragma unroll
  for (int i = 0; i < 3; ++i) {
#pragma unroll
    for (int j = 0; j < 3; ++j) {
      float I = (i == j) ? 1.0f : 0.0f;
      Rh[i*3+j] = __fadd_rn(
          __fadd_rn(__fmul_rn(cth, I), __fmul_rn(sth, K[i*3+j])),
          __fmul_rn(omc, Af));
      Sm[i*3+j] = __fadd_rn(__fmul_rn(sat, I), __fmul_rn(oms, lum[j]));
    }
  }
  mm3(SR, Sm, Rh);

  float* pp = W + b * PSTR;
#pragma unroll
  for (int i = 0; i < 9; ++i) pp[i] = M[i];
#pragma unroll
  for (int i = 0; i < 9; ++i) pp[9 + i] = __fmul_rn(bright, SR[i]);
  pp[18] = gammaf;

  const float* cu = cut + b * 5;
  pp[19] = (cu[0] < 0.5f) ? 1.0f : 0.0f;
  pp[20] = cu[1];
  pp[21] = cu[2];
  pp[22] = __fmul_rn(__fadd_rn(0.3f, __fmul_rn(0.2f, cu[3])), 0.5f);
  pp[23] = __fmul_rn(__fadd_rn(0.3f, __fmul_rn(0.2f, cu[4])), 0.5f);
}

// 4 x-consecutive pixels per thread; 1024 pixels per 256-thread block.
__global__ __launch_bounds__(256) void augment_kernel(
    const float* __restrict__ img, const float* __restrict__ W,
    float* __restrict__ out) {
  const int bkid = blockIdx.x;
  const int bb = bkid >> 8;                       // 256 blocks per batch
  const int p4 = (bkid * 256 + (int)threadIdx.x) * 4;
  const int rem = p4 & (HW - 1);
  const int yy = rem >> 9;
  const int xx0 = rem & (WDIM - 1);

  const float* pp = W + bb * PSTR;
  const float m00 = pp[0], m01 = pp[1], m02 = pp[2];
  const float m10 = pp[3], m11 = pp[4], m12 = pp[5];
  const float m20 = pp[6], m21 = pp[7], m22 = pp[8];
  const float c00 = pp[9],  c01 = pp[10], c02 = pp[11];
  const float c10 = pp[12], c11 = pp[13], c12 = pp[14];
  const float c20 = pp[15], c21 = pp[16], c22 = pp[17];
  const float gamma = pp[18];
  const float capply = pp[19], ccx = pp[20], ccy = pp[21];
  const float chw = pp[22], chh = pp[23];

  const float ysv = W[LIN11_OFF + yy];
  const float gy  = W[LIN01_OFF + yy];
  const float4 xsv = *(const float4*)(W + LIN11_OFF + xx0);
  const float4 gxv = *(const float4*)(W + LIN01_OFF + xx0);

  // y-dependent mask term is uniform across the 4 pixels
  const bool cuty = (capply != 0.0f) && (fabsf(__fsub_rn(gy, ccy)) < chh);

  const float* base = img + (size_t)bb * (HW * 3);
  float res[12];

  const float xsa[4] = {xsv.x, xsv.y, xsv.z, xsv.w};
  const float gxa[4] = {gxv.x, gxv.y, gxv.z, gxv.w};

#pragma unroll
  for (int i = 0; i < 4; ++i) {
    const float xs = xsa[i];
    // einsum: ((M0*x + M1*y) + M2), explicit IEEE mul/add (matches np)
    const float s0 = __fadd_rn(
        __fadd_rn(__fmul_rn(m00, xs), __fmul_rn(m01, ysv)), m02);
    const float s1 = __fadd_rn(
        __fadd_rn(__fmul_rn(m10, xs), __fmul_rn(m11, ysv)), m12);
    const float s2 = __fadd_rn(
        __fadd_rn(__fmul_rn(m20, xs), __fmul_rn(m21, ysv)), m22);
    const float u = __fdiv_rn(s0, s2);
    const float v = __fdiv_rn(s1, s2);
    const float px = __fmul_rn(__fmul_rn(__fadd_rn(u, 1.0f), 0.5f), 511.0f);
    const float py = __fmul_rn(__fmul_rn(__fadd_rn(v, 1.0f), 0.5f), 511.0f);

    const float vmask =
        (px >= 0.0f && px <= 511.0f && py >= 0.0f && py <= 511.0f) ? 1.0f
                                                                   : 0.0f;

    const float pxc = fminf(fmaxf(px, 0.0f), 511.0f);
    const float pyc = fminf(fmaxf(py, 0.0f), 511.0f);
    const float x0f = floorf(pxc), y0f = floorf(pyc);
    const float wx = pxc - x0f, wy = pyc - y0f;
    const int x0 = (int)x0f, y0 = (int)y0f;
    const int x1 = min(x0 + 1, WDIM - 1);
    const int y1 = min(y0 + 1, HDIM - 1);

    const float* p00 = base + (y0 * WDIM + x0) * 3;
    const float* p01 = base + (y0 * WDIM + x1) * 3;
    const float* p10 = base + (y1 * WDIM + x0) * 3;
    const float* p11 = base + (y1 * WDIM + x1) * 3;

    float w00 = (1.0f - wx) * (1.0f - wy);
    float w01 = wx * (1.0f - wy);
    float w10 = (1.0f - wx) * wy;
    float w11 = wx * wy;
    w00 *= vmask; w01 *= vmask; w10 *= vmask; w11 *= vmask;

    float r0, r1, r2;
    {
      float s;
      s = p00[0] * w00 + p01[0] * w01 + p10[0] * w10 + p11[0] * w11;
      s = fminf(fmaxf(s, 0.0f), 1.0f);
      r0 = __builtin_amdgcn_exp2f(gamma * __builtin_amdgcn_logf(s));
      s = p00[1] * w00 + p01[1] * w01 + p10[1] * w10 + p11[1] * w11;
      s = fminf(fmaxf(s, 0.0f), 1.0f);
      r1 = __builtin_amdgcn_exp2f(gamma * __builtin_amdgcn_logf(s));
      s = p00[2] * w00 + p01[2] * w01 + p10[2] * w10 + p11[2] * w11;
      s = fminf(fmaxf(s, 0.0f), 1.0f);
      r2 = __builtin_amdgcn_exp2f(gamma * __builtin_amdgcn_logf(s));
    }

    float q0 = fminf(fmaxf(c00 * r0 + c01 * r1 + c02 * r2, 0.0f), 1.0f);
    float q1 = fminf(fmaxf(c10 * r0 + c11 * r1 + c12 * r2, 0.0f), 1.0f);
    float q2 = fminf(fmaxf(c20 * r0 + c21 * r1 + c22 * r2, 0.0f), 1.0f);

    const bool cutm = cuty && (fabsf(__fsub_rn(gxa[i], ccx)) < chw);
    if (cutm) { q0 = 0.0f; q1 = 0.0f; q2 = 0.0f; }

    res[i * 3 + 0] = q0;
    res[i * 3 + 1] = q1;
    res[i * 3 + 2] = q2;
  }

  float4* o4 = (float4*)(out + (size_t)p4 * 3);
  o4[0] = make_float4(res[0], res[1], res[2],  res[3]);
  o4[1] = make_float4(res[4], res[5], res[6],  res[7]);
  o4[2] = make_float4(res[8], res[9], res[10], res[11]);
}

extern "C" void kernel_launch(void* const* d_in, const int* in_sizes, int n_in,
                              void* d_out, int out_size, void* d_ws, size_t ws_size,
                              hipStream_t stream) {
  const float* images = (const float*)d_in[0];
  const float* geom   = (const float*)d_in[1];
  const float* color  = (const float*)d_in[2];
  const float* cutu   = (const float*)d_in[3];
  float* W = (float*)d_ws;   // 2048 floats = 8 KB scratch

  setup_params<<<1, 512, 0, stream>>>(geom, color, cutu, W);

  const int npix = NB * HW;
  augment_kernel<<<npix / 1024, 256, 0, stream>>>(images, W, (float*)d_out);
}